// Round 1
// 4319.202 us; speedup vs baseline: 1.6903x; 1.6903x over previous
//
#include <hip/hip_runtime.h>
#include <stdint.h>

#define NN 64
#define TT 512
#define DD 512
#define HH 512
#define H3 1536
#define MROWS (NN * TT)   // 32768

typedef _Float16 f16;
typedef f16 f16x8 __attribute__((ext_vector_type(8)));
typedef float f32x4 __attribute__((ext_vector_type(4)));
typedef unsigned long long ull;

// ws layout (bytes):
//   xm    f16 [2][512][64][1536]                     201,326,592
//   wpack f16 [2][64][2 nt][16 ks][64 lane][8 j]       4,194,304
//   hbuf  f16 [2 buf][2 dir][64 seq][512 unit]           262,144
//   flags u32 [2 dir][64 blk]                                512
#define XM_BYTES    ((size_t)2 * TT * NN * H3 * 2)
#define WPACK_BYTES ((size_t)2 * 64 * 2 * 16 * 64 * 8 * 2)
#define HBUF_BYTES  ((size_t)2 * 2 * NN * HH * 2)
#define CNT_BYTES   ((size_t)512)

// ---------------------------------------------------------------------------
// Kernel 1: repack W_h fp32 -> f16 MFMA-B-fragment order. grid (64,2), 256 thr.
// ---------------------------------------------------------------------------
__global__ void repack_wh_frag(const float* __restrict__ whf,
                               const float* __restrict__ whb,
                               f16* __restrict__ wpack) {
    const int blk = blockIdx.x;
    const int dir = blockIdx.y;
    const float* src = dir ? whb : whf;
    f16* dst = wpack + ((size_t)(dir * 64 + blk)) * 16384;
    const int j0 = blk * 8;
    for (int c = threadIdx.x; c < 2048; c += blockDim.x) {
        const int lane = c & 63;
        const int nloc = ((c >> 10) << 4) + (lane & 15);   // 0..31 local col
        const int kq = ((c >> 6) & 15) * 32 + (lane >> 4) * 8;
        int gcol = 0;
        bool valid = true;
        if (nloc < 8)       gcol = j0 + nloc;
        else if (nloc < 16) gcol = 512 + j0 + (nloc - 8);
        else if (nloc < 24) gcol = 1024 + j0 + (nloc - 16);
        else valid = false;
        f16x8 v;
        #pragma unroll
        for (int j = 0; j < 8; ++j)
            v[j] = valid ? (f16)src[(size_t)(kq + j) * H3 + gcol] : (f16)0.f;
        *(f16x8*)(dst + (size_t)c * 8) = v;
    }
}

// ---------------------------------------------------------------------------
// Kernel 2: xm[dir][t][n][c] = x[n][t][:] @ W_x_dir[:, c]  (fp32 acc, f16 out)
// 128x128 tile, BK=32, 256 threads, 8x8 micro-tile. grid (12, 256, 2).
// ---------------------------------------------------------------------------
__global__ __launch_bounds__(256, 2) void gemm_xw(const float* __restrict__ x,
                                                  const float* __restrict__ wxf,
                                                  const float* __restrict__ wxb,
                                                  f16* __restrict__ xm) {
    const int dir = blockIdx.z;
    const float* w = dir ? wxb : wxf;
    f16* out = xm + (size_t)dir * MROWS * H3;
    const int c0 = blockIdx.x * 128;
    const int r0 = blockIdx.y * 128;
    __shared__ float sA[32][128];
    __shared__ float sB[32][128];
    const int t = threadIdx.x;
    const int tx = t & 15, ty = t >> 4;
    float acc[8][8];
    #pragma unroll
    for (int i = 0; i < 8; ++i)
        #pragma unroll
        for (int j = 0; j < 8; ++j) acc[i][j] = 0.f;

    for (int k0 = 0; k0 < DD; k0 += 32) {
        #pragma unroll
        for (int i = 0; i < 4; ++i) {
            int idx = t * 4 + i;
            int m = idx >> 3;
            int c = idx & 7;
            float4 u = *(const float4*)(x + (size_t)(r0 + m) * DD + k0 + c * 4);
            sA[c * 4 + 0][m] = u.x;
            sA[c * 4 + 1][m] = u.y;
            sA[c * 4 + 2][m] = u.z;
            sA[c * 4 + 3][m] = u.w;
        }
        #pragma unroll
        for (int i = 0; i < 4; ++i) {
            int idx = t * 4 + i;
            int kk = idx >> 5;
            int ch = idx & 31;
            *(float4*)&sB[kk][ch * 4] =
                *(const float4*)(w + (size_t)(k0 + kk) * H3 + c0 + ch * 4);
        }
        __syncthreads();
        for (int k = 0; k < 32; ++k) {
            float4 a0 = *(const float4*)&sA[k][ty * 8];
            float4 a1 = *(const float4*)&sA[k][ty * 8 + 4];
            float4 b0 = *(const float4*)&sB[k][tx * 8];
            float4 b1 = *(const float4*)&sB[k][tx * 8 + 4];
            float a[8] = {a0.x, a0.y, a0.z, a0.w, a1.x, a1.y, a1.z, a1.w};
            float b[8] = {b0.x, b0.y, b0.z, b0.w, b1.x, b1.y, b1.z, b1.w};
            #pragma unroll
            for (int ii = 0; ii < 8; ++ii)
                #pragma unroll
                for (int jj = 0; jj < 8; ++jj)
                    acc[ii][jj] = fmaf(a[ii], b[jj], acc[ii][jj]);
        }
        __syncthreads();
    }
    #pragma unroll
    for (int ii = 0; ii < 8; ++ii) {
        const size_t r = (size_t)(r0 + ty * 8 + ii);
        const size_t tt = r & 511, n = r >> 9;     // row = n*512 + t
        f16x8 v;
        #pragma unroll
        for (int jj = 0; jj < 8; ++jj) v[jj] = (f16)acc[ii][jj];
        *(f16x8*)(out + (tt * 64 + n) * H3 + c0 + tx * 8) = v;
    }
}

// ---------------------------------------------------------------------------
// Kernel 3: MFMA column-split GRU scan, fence-free device-coherent exchange.
// h-state is staged per step through LDS: one coalesced, deduplicated coherent
// read of the 64 KB slab per block (vs 8 strided per-wave fragment reloads),
// then XOR-swizzled ds_read_b128 fragment reads. Store/flag protocol unchanged.
// grid (64, 2), block 512 (8 waves: 4 mt x 2 nt).
// ---------------------------------------------------------------------------
__global__ __launch_bounds__(512, 1) void gru_scan_mfma(
        const f16* __restrict__ xm,
        const f16* __restrict__ wpack,
        const float* __restrict__ b_f, const float* __restrict__ b_b,
        f16* __restrict__ hbuf,
        unsigned int* __restrict__ flags,
        float* __restrict__ out) {
    const int blk = blockIdx.x;
    const int dir = blockIdx.y;
    const int tid = threadIdx.x;
    const int lane = tid & 63, wave = tid >> 6;
    const int mt = wave >> 1, nt = wave & 1;
    const int j0 = blk * 8;

    // 64 KB LDS: h slab image [64 seq][512 unit] f16, XOR-swizzled by
    // byte ^= ((row&7)<<4). pre[64][25] (6.4 KB) is overlaid on the same
    // region; an extra barrier separates fragment reads from pre writes.
    __shared__ __align__(16) unsigned char smem[65536];
    float (*pre)[25] = (float (*)[25])smem;

    // B-fragments: loaded once, resident for all 512 steps.
    f16x8 bfrag[16];
    {
        const f16* wp = wpack + (((size_t)(dir * 64 + blk) * 2 + nt)) * 8192;
        #pragma unroll
        for (int ks = 0; ks < 16; ++ks)
            bfrag[ks] = *(const f16x8*)(wp + ((size_t)(ks * 64 + lane)) * 8);
    }

    const int eseq = tid >> 3, eu = tid & 7;
    const float* bias = dir ? b_b : b_f;
    const float bz = bias[j0 + eu];
    const float br = bias[512 + j0 + eu];
    const float bg = bias[1024 + j0 + eu];
    const f16* xmd = xm + (size_t)dir * TT * NN * H3;
    f16* hb = hbuf + dir * (NN * HH);            // [buf][dir][seq][unit]
    unsigned int* fdir = flags + dir * 64;

    const int aseq = mt * 16 + (lane & 15);
    const int kb = (lane >> 4) * 8;
    const int pr0 = mt * 16 + ((lane >> 4) << 2);
    const int pc = nt * 16 + (lane & 15);
    const int fbase = aseq * 1024 + kb * 2;      // LDS byte base of fragment
    const int fswz = (aseq & 7) << 4;            // row-XOR swizzle

    float hprev = 0.f;
    int tc = dir ? (TT - 1) : 0;
    size_t xo = ((size_t)tc * 64 + eseq) * H3 + j0 + eu;
    float pxz = (float)xmd[xo];
    float pxr = (float)xmd[xo + 512];
    float pxg = (float)xmd[xo + 1024];

    union H16 { f16 h; unsigned short u; };

    for (int s = 0; s < TT; ++s) {
        // ---- stage h(s) -> LDS: coalesced agent-coherent loads (1 touch per
        //      64B line, no nt duplication), swizzled ds_write_b64 ----
        {
            const ull* hr8 = (const ull*)(hb + (s & 1) * (2 * NN * HH));
            ull tmp[16];
            #pragma unroll
            for (int i = 0; i < 16; ++i)
                tmp[i] = __hip_atomic_load(hr8 + i * 512 + tid,
                                           __ATOMIC_RELAXED, __HIP_MEMORY_SCOPE_AGENT);
            #pragma unroll
            for (int i = 0; i < 16; ++i) {
                const int off = (i * 512 + tid) * 8;
                const int row = off >> 10;
                *(ull*)(smem + (off ^ ((row & 7) << 4))) = tmp[i];
            }
        }
        __syncthreads();   // (D) LDS image of h(s) complete

        // ---- recurrent matmul: A-fragments via swizzled ds_read_b128 ----
        f32x4 acc = {0.f, 0.f, 0.f, 0.f};
        #pragma unroll
        for (int ks = 0; ks < 16; ++ks) {
            f16x8 av = *(const f16x8*)(smem + ((fbase + ks * 64) ^ fswz));
            acc = __builtin_amdgcn_mfma_f32_16x16x32_f16(av, bfrag[ks], acc, 0, 0, 0);
        }
        __syncthreads();   // (E) all waves done reading h image before pre overlay
        if (pc < 24) {
            #pragma unroll
            for (int r = 0; r < 4; ++r) pre[pr0 + r][pc] = acc[r];
        }
        __syncthreads();   // (A)

        // ---- gate math (thread owns (eseq, j0+eu)) ----
        const float z = 1.f / (1.f + __expf(-(pxz + pre[eseq][eu] + bz)));
        const float r = 1.f / (1.f + __expf(-(pxr + pre[eseq][8 + eu] + br)));
        const float g = 1.f - 2.f / (1.f + __expf(2.f * (pxg + r * pre[eseq][16 + eu] + bg)));
        const float hnew = (1.f - z) * g + z * hprev;
        hprev = hnew;
        out[((size_t)eseq * TT + tc) * 1024 + dir * 512 + j0 + eu] = hnew;

        // ---- publish h(s+1): packed u32 sc1 stores (even eu lanes) ----
        H16 hx; hx.h = (f16)hnew;
        const unsigned int ob = (unsigned int)__shfl_xor((int)hx.u, 1, 64);
        if (!(eu & 1)) {
            unsigned int pk = (unsigned int)hx.u | (ob << 16);
            f16* hw = hb + ((s + 1) & 1) * (2 * NN * HH) + eseq * HH + j0 + eu;
            __hip_atomic_store((unsigned int*)hw, pk,
                               __ATOMIC_RELAXED, __HIP_MEMORY_SCOPE_AGENT);
        }

        if (s < TT - 1) {
            // prefetch next x-projection (plain cached loads, overlap the wait)
            const int tcn = dir ? (TT - 2 - s) : (s + 1);
            const size_t xo2 = ((size_t)tcn * 64 + eseq) * H3 + j0 + eu;
            pxz = (float)xmd[xo2];
            pxr = (float)xmd[xo2 + 512];
            pxg = (float)xmd[xo2 + 1024];
            tc = tcn;
            __syncthreads();   // (B) drains vmcnt: this block's h stores reached IC
            if (wave == 0) {
                if (lane == 0)
                    __hip_atomic_store(&fdir[blk], (unsigned int)(s + 1),
                                       __ATOMIC_RELAXED, __HIP_MEMORY_SCOPE_AGENT);
                const unsigned int tgt = (unsigned int)(s + 1);
                while (true) {
                    unsigned int v = __hip_atomic_load(&fdir[lane],
                                __ATOMIC_RELAXED, __HIP_MEMORY_SCOPE_AGENT);
                    if (__all(v >= tgt)) break;
                    __builtin_amdgcn_s_sleep(2);
                }
            }
            __syncthreads();   // (C) all waves held until every block published h
        }
    }
}

// ---------------------------------------------------------------------------
// Zero-workspace fallback (correct but slow).
// ---------------------------------------------------------------------------
__global__ __launch_bounds__(512) void gru_scan_fused(const float* __restrict__ x,
                                                      const float* __restrict__ wxf,
                                                      const float* __restrict__ whf,
                                                      const float* __restrict__ b_f,
                                                      const float* __restrict__ wxb,
                                                      const float* __restrict__ whb,
                                                      const float* __restrict__ b_b,
                                                      float* __restrict__ out) {
    const int n = blockIdx.x;
    const int dir = blockIdx.y;
    const int tid = threadIdx.x;
    const float* wx = dir ? wxb : wxf;
    const float* wh = dir ? whb : whf;
    const float* bias = dir ? b_b : b_f;
    const float bz = bias[tid];
    const float br = bias[512 + tid];
    const float bg = bias[1024 + tid];

    __shared__ float sh[512];
    __shared__ float shx[512];
    sh[tid] = 0.f;
    float hprev = 0.f;
    __syncthreads();

    for (int s = 0; s < TT; ++s) {
        const int tc = dir ? (TT - 1 - s) : s;
        shx[tid] = x[((size_t)n * TT + tc) * DD + tid];
        __syncthreads();
        float az = 0.f, ar = 0.f, ag = 0.f;
        float xz = 0.f, xr = 0.f, xg = 0.f;
        #pragma unroll 2
        for (int k = 0; k < DD; ++k) {
            const float hk = sh[k];
            const float xk = shx[k];
            const size_t rowb = (size_t)k * H3 + tid;
            az = fmaf(wh[rowb], hk, az);
            ar = fmaf(wh[rowb + 512], hk, ar);
            ag = fmaf(wh[rowb + 1024], hk, ag);
            xz = fmaf(wx[rowb], xk, xz);
            xr = fmaf(wx[rowb + 512], xk, xr);
            xg = fmaf(wx[rowb + 1024], xk, xg);
        }
        const float z = 1.f / (1.f + __expf(-(xz + az + bz)));
        const float r = 1.f / (1.f + __expf(-(xr + ar + br)));
        const float g = 1.f - 2.f / (1.f + __expf(2.f * (xg + r * ag + bg)));
        const float hnew = (1.f - z) * g + z * hprev;
        __syncthreads();
        sh[tid] = hnew;
        hprev = hnew;
        out[((size_t)n * TT + tc) * 1024 + (size_t)dir * 512 + tid] = hnew;
        __syncthreads();
    }
}

// ---------------------------------------------------------------------------
extern "C" void kernel_launch(void* const* d_in, const int* in_sizes, int n_in,
                              void* d_out, int out_size, void* d_ws, size_t ws_size,
                              hipStream_t stream) {
    const float* x   = (const float*)d_in[0];
    const float* wxf = (const float*)d_in[1];
    const float* whf = (const float*)d_in[2];
    const float* bf_ = (const float*)d_in[3];
    const float* wxb = (const float*)d_in[4];
    const float* whb = (const float*)d_in[5];
    const float* bb_ = (const float*)d_in[6];
    float* out = (float*)d_out;

    const size_t need = XM_BYTES + WPACK_BYTES + HBUF_BYTES + CNT_BYTES; // ~206 MB

    if (ws_size >= need) {
        f16* xm = (f16*)d_ws;
        f16* wpack = (f16*)((char*)d_ws + XM_BYTES);
        f16* hbuf = (f16*)((char*)d_ws + XM_BYTES + WPACK_BYTES);
        unsigned int* flags = (unsigned int*)((char*)d_ws + XM_BYTES + WPACK_BYTES + HBUF_BYTES);
        // zero h state (h0 = 0) and the per-block step flags
        hipMemsetAsync(hbuf, 0, HBUF_BYTES + CNT_BYTES, stream);
        repack_wh_frag<<<dim3(64, 2), 256, 0, stream>>>(whf, whb, wpack);
        gemm_xw<<<dim3(12, 256, 2), 256, 0, stream>>>(x, wxf, wxb, xm);
        gru_scan_mfma<<<dim3(64, 2), 512, 0, stream>>>(xm, wpack, bf_, bb_,
                                                       hbuf, flags, out);
    } else {
        gru_scan_fused<<<dim3(64, 2), 512, 0, stream>>>(x, wxf, whf, bf_,
                                                        wxb, whb, bb_, out);
    }
}

// Round 3
// 3330.781 us; speedup vs baseline: 2.1919x; 1.2968x over previous
//
#include <hip/hip_runtime.h>
#include <stdint.h>

#define NN 64
#define TT 512
#define DD 512
#define HH 512
#define H3 1536
#define MROWS (NN * TT)   // 32768

#define GRPN 4      // n-groups per dir
#define CBLK 8      // col-blocks per group (rendezvous group size)
#define MN 16       // sequences per n-group

typedef _Float16 f16;
typedef f16 f16x8 __attribute__((ext_vector_type(8)));
typedef float f32x4 __attribute__((ext_vector_type(4)));
typedef unsigned long long ull;

// ws layout (bytes):
//   xm    f16 [2][512][64][1536]                         201,326,592
//   wpack f16 [2][8 cb][8 w][3 t][8 ks][64 lane][8]        3,145,728
//   hbuf  ull [2 buf][2 dir][4 g][16 n][256 slots]           524,288
//         slot = (u32: 2xf16 h) | (u32 stamp << 32)
//   flags u32 [2 dir][4 g][16 (8 used)] = read-done steps         512
#define XM_BYTES    ((size_t)2 * TT * NN * H3 * 2)
#define WPACK_BYTES ((size_t)2 * CBLK * 8 * 3 * 8 * 64 * 8 * 2)
#define HBUF_BYTES  ((size_t)2 * 2 * GRPN * MN * 256 * 8)
#define CNT_BYTES   ((size_t)512)

// ---------------------------------------------------------------------------
// Kernel 1: repack W_h fp32 -> f16 MFMA-B-fragment order.
// Layout: [dir][cb][wave][t(z,r,g)][ks][lane][8j], wave = kh*4 + ug.
//   k = kh*256 + ks*32 + (lane>>4)*8 + j;  col = t*512 + cb*64 + ug*16 + (lane&15)
// grid (8, 2), 256 threads.
// ---------------------------------------------------------------------------
__global__ void repack_wh_frag(const float* __restrict__ whf,
                               const float* __restrict__ whb,
                               f16* __restrict__ wpack) {
    const int cb = blockIdx.x;
    const int dir = blockIdx.y;
    const float* src = dir ? whb : whf;
    f16* dst = wpack + ((size_t)(dir * CBLK + cb)) * 12288 * 8;
    for (int c = threadIdx.x; c < 12288; c += blockDim.x) {
        const int lane = c & 63;
        const int ks = (c >> 6) & 7;
        const int q2 = c >> 9;          // 0..23 = w*3 + t
        const int t = q2 % 3;
        const int w = q2 / 3;
        const int k = (w >> 2) * 256 + ks * 32 + (lane >> 4) * 8;
        const int u = cb * 64 + (w & 3) * 16 + (lane & 15);
        const int gcol = t * 512 + u;
        f16x8 v;
        #pragma unroll
        for (int j = 0; j < 8; ++j)
            v[j] = (f16)src[(size_t)(k + j) * H3 + gcol];
        *(f16x8*)(dst + (size_t)c * 8) = v;
    }
}

// ---------------------------------------------------------------------------
// Kernel 2: xm[dir][t][n][c] = x[n][t][:] @ W_x_dir[:, c]  (fp32 acc, f16 out)
// 128x128 tile, BK=32, 256 threads, 8x8 micro-tile. grid (12, 256, 2).
// ---------------------------------------------------------------------------
__global__ __launch_bounds__(256, 2) void gemm_xw(const float* __restrict__ x,
                                                  const float* __restrict__ wxf,
                                                  const float* __restrict__ wxb,
                                                  f16* __restrict__ xm) {
    const int dir = blockIdx.z;
    const float* w = dir ? wxb : wxf;
    f16* out = xm + (size_t)dir * MROWS * H3;
    const int c0 = blockIdx.x * 128;
    const int r0 = blockIdx.y * 128;
    __shared__ float sA[32][128];
    __shared__ float sB[32][128];
    const int t = threadIdx.x;
    const int tx = t & 15, ty = t >> 4;
    float acc[8][8];
    #pragma unroll
    for (int i = 0; i < 8; ++i)
        #pragma unroll
        for (int j = 0; j < 8; ++j) acc[i][j] = 0.f;

    for (int k0 = 0; k0 < DD; k0 += 32) {
        #pragma unroll
        for (int i = 0; i < 4; ++i) {
            int idx = t * 4 + i;
            int m = idx >> 3;
            int c = idx & 7;
            float4 u = *(const float4*)(x + (size_t)(r0 + m) * DD + k0 + c * 4);
            sA[c * 4 + 0][m] = u.x;
            sA[c * 4 + 1][m] = u.y;
            sA[c * 4 + 2][m] = u.z;
            sA[c * 4 + 3][m] = u.w;
        }
        #pragma unroll
        for (int i = 0; i < 4; ++i) {
            int idx = t * 4 + i;
            int kk = idx >> 5;
            int ch = idx & 31;
            *(float4*)&sB[kk][ch * 4] =
                *(const float4*)(w + (size_t)(k0 + kk) * H3 + c0 + ch * 4);
        }
        __syncthreads();
        for (int k = 0; k < 32; ++k) {
            float4 a0 = *(const float4*)&sA[k][ty * 8];
            float4 a1 = *(const float4*)&sA[k][ty * 8 + 4];
            float4 b0 = *(const float4*)&sB[k][tx * 8];
            float4 b1 = *(const float4*)&sB[k][tx * 8 + 4];
            float a[8] = {a0.x, a0.y, a0.z, a0.w, a1.x, a1.y, a1.z, a1.w};
            float b[8] = {b0.x, b0.y, b0.z, b0.w, b1.x, b1.y, b1.z, b1.w};
            #pragma unroll
            for (int ii = 0; ii < 8; ++ii)
                #pragma unroll
                for (int jj = 0; jj < 8; ++jj)
                    acc[ii][jj] = fmaf(a[ii], b[jj], acc[ii][jj]);
        }
        __syncthreads();
    }
    #pragma unroll
    for (int ii = 0; ii < 8; ++ii) {
        const size_t r = (size_t)(r0 + ty * 8 + ii);
        const size_t tt = r & 511, n = r >> 9;     // row = n*512 + t
        f16x8 v;
        #pragma unroll
        for (int jj = 0; jj < 8; ++jj) v[jj] = (f16)acc[ii][jj];
        *(f16x8*)(out + (tt * 64 + n) * H3 + c0 + tx * 8) = v;
    }
}

// ---------------------------------------------------------------------------
// Kernel 3: 2-D split GRU scan with STAMPED-SLOT exchange (race-free by
// construction):
//  - each 8B slot = (2xf16 h, step stamp) written by ONE atomic store; a slot
//    can never show stamp s with old data.
//  - readers retry slots whose stamp < s: late/in-flight stores are absorbed.
//  - anti-clobber: RD[cb]=s+1 posted AFTER barrier (D) (loads already in
//    registers -> causally sound regardless of store-visibility ordering);
//    publishers gate on RD >= s (1-step lagged, normally zero wait).
//  - no end-of-step rendezvous, no store-drain on the critical path.
// grid (8, 4, 2), 512 threads = 8 waves (kh = k-half, ug = 16-unit group).
// ---------------------------------------------------------------------------
__global__ __launch_bounds__(512, 1) void gru_scan_mfma(
        const f16* __restrict__ xm,
        const f16* __restrict__ wpack,
        const float* __restrict__ b_f, const float* __restrict__ b_b,
        ull* __restrict__ hbuf,
        unsigned int* __restrict__ flags,
        float* __restrict__ out) {
    const int cb  = blockIdx.x;
    const int g   = blockIdx.y;
    const int dir = blockIdx.z;
    const int tid = threadIdx.x;
    const int lane = tid & 63, wave = tid >> 6;
    const int kh = wave >> 2;          // k-half: [kh*256, kh*256+256)
    const int ug = wave & 3;           // unit group: [ug*16, ug*16+16)

    // LDS: h image [16 n][512 u] f16, XOR-swizzled (byte ^= (row&7)<<4), 16 KB
    //      + k-partial exchange part[ug][t][16 n][20 pad] f32, 15 KB
    __shared__ __align__(16) unsigned char himg[16384];
    __shared__ float part[4][3][16][20];

    // B-fragments: resident for all 512 steps (96 VGPR).
    f16x8 bfrag[3][8];
    {
        const f16* wp = wpack +
            ((size_t)(dir * CBLK + cb) * 12288 + (size_t)wave * 1536) * 8;
        #pragma unroll
        for (int t = 0; t < 3; ++t)
            #pragma unroll
            for (int ks = 0; ks < 8; ++ks)
                bfrag[t][ks] = *(const f16x8*)(wp + ((size_t)((t * 8 + ks) * 64 + lane)) * 8);
    }

    const int u_l = cb * 64 + ug * 16 + (lane & 15);  // unit col (kh==0 duty)
    const int nrow0 = (lane >> 4) * 4;                // first of 4 local n-rows
    const float* bias = dir ? b_b : b_f;
    float bz = 0.f, br = 0.f, bg = 0.f;
    if (kh == 0) { bz = bias[u_l]; br = bias[512 + u_l]; bg = bias[1024 + u_l]; }
    const f16* xmd = xm + (size_t)dir * TT * NN * H3;
    unsigned int* rdg = flags + (dir * GRPN + g) * 16;   // 64B line per group

    // A-fragment LDS address: row m = lane&15, k = kh*256 + ks*32 + (lane>>4)*8
    const int fb = (lane & 15) * 1024 + kh * 512 + (lane >> 4) * 16;
    const int fswz = ((lane & 15) & 7) << 4;

    float hprev[4] = {0.f, 0.f, 0.f, 0.f};
    float px[3][4];
    float hnew[4];
    union H16 { f16 h; unsigned short u; };

    for (int s = 0; s < TT; ++s) {
        const int tc = dir ? (TT - 1 - s) : s;

        // xm gate inputs (plain cached loads; latency overlaps staging)
        if (kh == 0) {
            #pragma unroll
            for (int r = 0; r < 4; ++r) {
                const int n = g * 16 + nrow0 + r;
                const size_t ro = ((size_t)tc * 64 + n) * H3 + u_l;
                px[0][r] = (float)xmd[ro];
                px[1][r] = (float)xmd[ro + 512];
                px[2][r] = (float)xmd[ro + 1024];
            }
        }

        // ---- stage h(s): stamped slots, retry until stamp >= s ----
        {
            const ull* hr8 = hbuf +
                (((size_t)(s & 1) * 2 + dir) * GRPN + g) * 4096;
            ull tmp[8];
            #pragma unroll
            for (int i = 0; i < 8; ++i)
                tmp[i] = __hip_atomic_load(hr8 + i * 512 + tid,
                                           __ATOMIC_RELAXED, __HIP_MEMORY_SCOPE_AGENT);
            const unsigned int want = (unsigned int)s;
            for (;;) {
                bool bad = false;
                #pragma unroll
                for (int i = 0; i < 8; ++i)
                    bad |= ((unsigned int)(tmp[i] >> 32) < want);
                if (!__any(bad)) break;
                #pragma unroll
                for (int i = 0; i < 8; ++i)
                    if ((unsigned int)(tmp[i] >> 32) < want)
                        tmp[i] = __hip_atomic_load(hr8 + i * 512 + tid,
                                                   __ATOMIC_RELAXED, __HIP_MEMORY_SCOPE_AGENT);
                __builtin_amdgcn_s_sleep(1);
            }
            #pragma unroll
            for (int i = 0; i < 8; ++i) {
                const int off = (i * 512 + tid) * 4;   // 4B of h per slot
                const int row = off >> 10;
                *(unsigned int*)(himg + (off ^ ((row & 7) << 4))) =
                    (unsigned int)tmp[i];
            }
        }
        __syncthreads();   // (D) h image complete; all staging loads done

        // read-done: causally sound (loads completed before this store issues)
        if (tid == 0)
            __hip_atomic_store(&rdg[cb], (unsigned int)(s + 1),
                               __ATOMIC_RELAXED, __HIP_MEMORY_SCOPE_AGENT);

        // ---- recurrent matmul: 3 N-tiles (z,r,g) x 8 ks over this k-half ----
        f32x4 a0 = {0.f, 0.f, 0.f, 0.f};
        f32x4 a1 = {0.f, 0.f, 0.f, 0.f};
        f32x4 a2 = {0.f, 0.f, 0.f, 0.f};
        #pragma unroll
        for (int ks = 0; ks < 8; ++ks) {
            f16x8 av = *(const f16x8*)(himg + ((fb + ks * 64) ^ fswz));
            a0 = __builtin_amdgcn_mfma_f32_16x16x32_f16(av, bfrag[0][ks], a0, 0, 0, 0);
            a1 = __builtin_amdgcn_mfma_f32_16x16x32_f16(av, bfrag[1][ks], a1, 0, 0, 0);
            a2 = __builtin_amdgcn_mfma_f32_16x16x32_f16(av, bfrag[2][ks], a2, 0, 0, 0);
        }
        if (kh == 1) {
            #pragma unroll
            for (int r = 0; r < 4; ++r) {
                part[ug][0][nrow0 + r][lane & 15] = a0[r];
                part[ug][1][nrow0 + r][lane & 15] = a1[r];
                part[ug][2][nrow0 + r][lane & 15] = a2[r];
            }
        }
        __syncthreads();   // (E) partials visible

        if (kh == 0) {
            // ---- k-reduce + gate math: z,r,g all local to this lane ----
            #pragma unroll
            for (int r = 0; r < 4; ++r) {
                const float sz = px[0][r] + a0[r] + part[ug][0][nrow0 + r][lane & 15] + bz;
                const float sr = px[1][r] + a1[r] + part[ug][1][nrow0 + r][lane & 15] + br;
                const float hg = a2[r] + part[ug][2][nrow0 + r][lane & 15];
                const float z  = 1.f / (1.f + __expf(-sz));
                const float rr = 1.f / (1.f + __expf(-sr));
                const float gg = 1.f - 2.f / (1.f + __expf(2.f * (px[2][r] + rr * hg + bg)));
                hnew[r] = (1.f - z) * gg + z * hprev[r];
                hprev[r] = hnew[r];
            }
        } else if (wave == 4 && s > 0) {
            // anti-clobber gate (1-step lagged, normally already satisfied):
            // publish of h(s+1) overwrites h(s-1); need all RD >= s.
            const unsigned int tgt = (unsigned int)s;
            while (true) {
                unsigned int v = __hip_atomic_load(&rdg[lane & 7],
                            __ATOMIC_RELAXED, __HIP_MEMORY_SCOPE_AGENT);
                if (__all(v >= tgt)) break;
                __builtin_amdgcn_s_sleep(1);
            }
        }
        __syncthreads();   // (F) himg reads done + clobber gate passed

        if (kh == 0) {
            #pragma unroll
            for (int r = 0; r < 4; ++r) {
                const int n = g * 16 + nrow0 + r;
                out[((size_t)n * TT + tc) * 1024 + dir * 512 + u_l] = hnew[r];
            }
            if (s < TT - 1) {
                // ---- publish h(s+1): (pair, stamp) in ONE 8B atomic ----
                ull* nslab = hbuf +
                    (((size_t)((s + 1) & 1) * 2 + dir) * GRPN + g) * 4096;
                #pragma unroll
                for (int r = 0; r < 4; ++r) {
                    H16 hx; hx.h = (f16)hnew[r];
                    const unsigned int ob = (unsigned int)__shfl_xor((int)hx.u, 1, 64);
                    if (!(lane & 1)) {
                        const ull pk = (ull)((unsigned int)hx.u | (ob << 16))
                                     | ((ull)(s + 1) << 32);
                        __hip_atomic_store(nslab + (nrow0 + r) * 256 + (u_l >> 1),
                                           pk, __ATOMIC_RELAXED, __HIP_MEMORY_SCOPE_AGENT);
                    }
                }
            }
        }
        // no end-of-step barrier: stamps handle data-ready, RD handles clobber
    }
}

// ---------------------------------------------------------------------------
// Zero-workspace fallback (correct but slow).
// ---------------------------------------------------------------------------
__global__ __launch_bounds__(512) void gru_scan_fused(const float* __restrict__ x,
                                                      const float* __restrict__ wxf,
                                                      const float* __restrict__ whf,
                                                      const float* __restrict__ b_f,
                                                      const float* __restrict__ wxb,
                                                      const float* __restrict__ whb,
                                                      const float* __restrict__ b_b,
                                                      float* __restrict__ out) {
    const int n = blockIdx.x;
    const int dir = blockIdx.y;
    const int tid = threadIdx.x;
    const float* wx = dir ? wxb : wxf;
    const float* wh = dir ? whb : whf;
    const float* bias = dir ? b_b : b_f;
    const float bz = bias[tid];
    const float br = bias[512 + tid];
    const float bg = bias[1024 + tid];

    __shared__ float sh[512];
    __shared__ float shx[512];
    sh[tid] = 0.f;
    float hprev = 0.f;
    __syncthreads();

    for (int s = 0; s < TT; ++s) {
        const int tc = dir ? (TT - 1 - s) : s;
        shx[tid] = x[((size_t)n * TT + tc) * DD + tid];
        __syncthreads();
        float az = 0.f, ar = 0.f, ag = 0.f;
        float xz = 0.f, xr = 0.f, xg = 0.f;
        #pragma unroll 2
        for (int k = 0; k < DD; ++k) {
            const float hk = sh[k];
            const float xk = shx[k];
            const size_t rowb = (size_t)k * H3 + tid;
            az = fmaf(wh[rowb], hk, az);
            ar = fmaf(wh[rowb + 512], hk, ar);
            ag = fmaf(wh[rowb + 1024], hk, ag);
            xz = fmaf(wx[rowb], xk, xz);
            xr = fmaf(wx[rowb + 512], xk, xr);
            xg = fmaf(wx[rowb + 1024], xk, xg);
        }
        const float z = 1.f / (1.f + __expf(-(xz + az + bz)));
        const float r = 1.f / (1.f + __expf(-(xr + ar + br)));
        const float g = 1.f - 2.f / (1.f + __expf(2.f * (xg + r * ag + bg)));
        const float hnew = (1.f - z) * g + z * hprev;
        __syncthreads();
        sh[tid] = hnew;
        hprev = hnew;
        out[((size_t)n * TT + tc) * 1024 + (size_t)dir * 512 + tid] = hnew;
        __syncthreads();
    }
}

// ---------------------------------------------------------------------------
extern "C" void kernel_launch(void* const* d_in, const int* in_sizes, int n_in,
                              void* d_out, int out_size, void* d_ws, size_t ws_size,
                              hipStream_t stream) {
    const float* x   = (const float*)d_in[0];
    const float* wxf = (const float*)d_in[1];
    const float* whf = (const float*)d_in[2];
    const float* bf_ = (const float*)d_in[3];
    const float* wxb = (const float*)d_in[4];
    const float* whb = (const float*)d_in[5];
    const float* bb_ = (const float*)d_in[6];
    float* out = (float*)d_out;

    const size_t need = XM_BYTES + WPACK_BYTES + HBUF_BYTES + CNT_BYTES; // ~205 MB

    if (ws_size >= need) {
        f16* xm = (f16*)d_ws;
        f16* wpack = (f16*)((char*)d_ws + XM_BYTES);
        ull* hbuf = (ull*)((char*)d_ws + XM_BYTES + WPACK_BYTES);
        unsigned int* flags = (unsigned int*)((char*)d_ws + XM_BYTES + WPACK_BYTES + HBUF_BYTES);
        // zero h slabs (h0 = 0, stamp 0 == valid for step 0) and RD flags
        hipMemsetAsync(hbuf, 0, HBUF_BYTES + CNT_BYTES, stream);
        repack_wh_frag<<<dim3(CBLK, 2), 256, 0, stream>>>(whf, whb, wpack);
        gemm_xw<<<dim3(12, 256, 2), 256, 0, stream>>>(x, wxf, wxb, xm);
        gru_scan_mfma<<<dim3(CBLK, GRPN, 2), 512, 0, stream>>>(xm, wpack, bf_, bb_,
                                                               hbuf, flags, out);
    } else {
        gru_scan_fused<<<dim3(64, 2), 512, 0, stream>>>(x, wxf, whf, bf_,
                                                        wxb, whb, bb_, out);
    }
}